// Round 1
// baseline (121.824 us; speedup 1.0000x reference)
//
#include <hip/hip_runtime.h>
#include <math.h>

#define NBR   64
#define DDIM  256
#define NF    8
#define EPSN  1e-12f

// One block per batch row b. 256 threads = 4 waves.
// Lane l (0..63) owns facet f = l>>3 and 4 consecutive emb elems e0 = (l&7)*4.
// Wave g handles neighbors n = 4*i + g, i = 0..15.
// Normalized neighbor fragments stay in registers (zn[16]) across both passes,
// so the 512 MB neighbor tensor is read from HBM exactly once.
__global__ __launch_bounds__(256) void homo_attn_kernel(
    const float* __restrict__ features,      // [B, 256]
    const float* __restrict__ neigh,         // [B, 64, 256]
    float* __restrict__ out)                 // [B, 256]
{
    const int b   = blockIdx.x;
    const int tid = threadIdx.x;
    const int g   = tid >> 6;   // wave id 0..3
    const int l   = tid & 63;   // lane 0..63
    const int f   = l >> 3;     // facet 0..7
    const int sub = l & 7;      // slot within the 8-lane e-group

    __shared__ float  sLogit[NBR * NF];   // [n][f], 2 KB
    __shared__ float  sM[NF];
    __shared__ float  sInvS[NF];
    __shared__ float4 sPart[4 * 64];      // per-wave partial output rows, 4 KB

    // ---- load + normalize this lane's x fragment (facet f, 4 elems) ----
    const float4 x4 = *reinterpret_cast<const float4*>(
        features + (size_t)b * DDIM + (size_t)l * 4);
    float xs = x4.x * x4.x + x4.y * x4.y + x4.z * x4.z + x4.w * x4.w;
    xs += __shfl_xor(xs, 1);
    xs += __shfl_xor(xs, 2);
    xs += __shfl_xor(xs, 4);
    const float xinv = 1.0f / fmaxf(sqrtf(xs), EPSN);
    const float xnx = x4.x * xinv, xny = x4.y * xinv;
    const float xnz = x4.z * xinv, xnw = x4.w * xinv;

    const float* zrow = neigh + (size_t)b * (NBR * DDIM);

    float4 zn[16];   // normalized neighbor fragments, held in VGPRs

    // ---- pass 1: load, normalize, cosine logits ----
    #pragma unroll
    for (int i = 0; i < 16; ++i) {
        const int n = i * 4 + g;
        float4 z4 = *reinterpret_cast<const float4*>(
            zrow + (size_t)n * DDIM + (size_t)l * 4);
        float zs = z4.x * z4.x + z4.y * z4.y + z4.z * z4.z + z4.w * z4.w;
        zs += __shfl_xor(zs, 1);
        zs += __shfl_xor(zs, 2);
        zs += __shfl_xor(zs, 4);
        const float zinv = 1.0f / fmaxf(sqrtf(zs), EPSN);
        z4.x *= zinv; z4.y *= zinv; z4.z *= zinv; z4.w *= zinv;
        zn[i] = z4;
        float dt = z4.x * xnx + z4.y * xny + z4.z * xnz + z4.w * xnw;
        dt += __shfl_xor(dt, 1);
        dt += __shfl_xor(dt, 2);
        dt += __shfl_xor(dt, 4);
        if (sub == 0) sLogit[n * NF + f] = dt;
    }
    __syncthreads();

    // ---- softmax stats over n per facet (wave 0 only) ----
    if (tid < 64) {
        const int ff = tid >> 3;   // facet
        const int j  = tid & 7;    // n-strided slot
        float mx = -1e30f;
        #pragma unroll
        for (int k = 0; k < 8; ++k)
            mx = fmaxf(mx, sLogit[(j + k * 8) * NF + ff]);
        mx = fmaxf(mx, __shfl_xor(mx, 1));
        mx = fmaxf(mx, __shfl_xor(mx, 2));
        mx = fmaxf(mx, __shfl_xor(mx, 4));
        float s = 0.0f;
        #pragma unroll
        for (int k = 0; k < 8; ++k)
            s += __expf(sLogit[(j + k * 8) * NF + ff] - mx);
        s += __shfl_xor(s, 1);
        s += __shfl_xor(s, 2);
        s += __shfl_xor(s, 4);
        if (j == 0) { sM[ff] = mx; sInvS[ff] = 1.0f / s; }
    }
    __syncthreads();

    // ---- pass 2: weighted sum over this wave's neighbors (registers) ----
    const float m  = sM[f];
    const float is = sInvS[f];
    float ux = 0.0f, uy = 0.0f, uz = 0.0f, uw = 0.0f;
    #pragma unroll
    for (int i = 0; i < 16; ++i) {
        const int n = i * 4 + g;
        const float w = __expf(sLogit[n * NF + f] - m) * is;
        ux += zn[i].x * w;
        uy += zn[i].y * w;
        uz += zn[i].z * w;
        uw += zn[i].w * w;
    }
    sPart[g * 64 + l] = make_float4(ux, uy, uz, uw);
    __syncthreads();

    // ---- cross-wave reduce + coalesced store ----
    const float* sp = reinterpret_cast<const float*>(sPart);
    const float v = sp[tid] + sp[256 + tid] + sp[512 + tid] + sp[768 + tid];
    out[(size_t)b * DDIM + tid] = v;
}

extern "C" void kernel_launch(void* const* d_in, const int* in_sizes, int n_in,
                              void* d_out, int out_size, void* d_ws, size_t ws_size,
                              hipStream_t stream) {
    const float* features = (const float*)d_in[0];
    const float* neigh    = (const float*)d_in[1];
    float* out            = (float*)d_out;
    const int B = in_sizes[0] / DDIM;
    homo_attn_kernel<<<B, 256, 0, stream>>>(features, neigh, out);
}

// Round 2
// 111.082 us; speedup vs baseline: 1.0967x; 1.0967x over previous
//
#include <hip/hip_runtime.h>
#include <math.h>

#define NBR   64
#define DDIM  256
#define EPSN  1e-12f

// Sum over each aligned 8-lane group (lanes sharing l>>3), result broadcast
// to all 8 lanes. xor1/xor2 via DPP quad_perm (VALU pipe), xor4 via
// ds_swizzle BitMode 0x101F (DS pipe). 2 DS ops per reduction instead of 3.
__device__ __forceinline__ float grp8_sum(float v) {
    v += __int_as_float(__builtin_amdgcn_update_dpp(
            __float_as_int(v), __float_as_int(v), 0xB1, 0xF, 0xF, true)); // xor 1
    v += __int_as_float(__builtin_amdgcn_update_dpp(
            __float_as_int(v), __float_as_int(v), 0x4E, 0xF, 0xF, true)); // xor 2
    v += __int_as_float(__builtin_amdgcn_ds_swizzle(
            __float_as_int(v), 0x101F));                                  // xor 4
    return v;
}

// One WAVE per batch row. Lane l owns facet f = l>>3, elems e = (l&7)*4 .. +3.
// Single streaming pass over the 64 neighbors with unshifted softmax
// (logits are cosine sims in [-1,1], so exp needs no max subtraction).
// No LDS, no barriers; normalized-x in registers; s and u accumulate online.
__global__ __launch_bounds__(256, 8) void homo_attn_kernel(
    const float* __restrict__ features,      // [B, 256]
    const float* __restrict__ neigh,         // [B, 64, 256]
    float* __restrict__ out,                 // [B, 256]
    int B)
{
    const int row = (blockIdx.x << 2) + (threadIdx.x >> 6);  // one wave = one b
    if (row >= B) return;
    const int l = threadIdx.x & 63;

    // ---- x fragment: load + l2-normalize ----
    const float4 x4 = *reinterpret_cast<const float4*>(
        features + (size_t)row * DDIM + (size_t)l * 4);
    const float xs = grp8_sum(x4.x * x4.x + x4.y * x4.y + x4.z * x4.z + x4.w * x4.w);
    const float xinv = 1.0f / fmaxf(sqrtf(xs), EPSN);
    const float xnx = x4.x * xinv, xny = x4.y * xinv;
    const float xnz = x4.z * xinv, xnw = x4.w * xinv;

    const float* zp = neigh + (size_t)row * (NBR * DDIM) + (size_t)l * 4;

    // ---- single pass over neighbors: logits + online weighted sum ----
    float ux = 0.0f, uy = 0.0f, uz = 0.0f, uw = 0.0f, s = 0.0f;
    #pragma unroll 4
    for (int n = 0; n < NBR; ++n) {
        const float4 z4 = *reinterpret_cast<const float4*>(zp + (size_t)n * DDIM);
        const float zs = grp8_sum(z4.x * z4.x + z4.y * z4.y + z4.z * z4.z + z4.w * z4.w);
        const float zinv = 1.0f / fmaxf(sqrtf(zs), EPSN);       // uniform in group
        const float dt = grp8_sum(z4.x * xnx + z4.y * xny +
                                  z4.z * xnz + z4.w * xnw) * zinv;  // cosine in [-1,1]
        const float p = __expf(dt);        // no max shift needed: |dt| <= 1
        const float w = p * zinv;          // fold z-normalization into the weight
        s  += p;
        ux += w * z4.x; uy += w * z4.y; uz += w * z4.z; uw += w * z4.w;
    }

    const float is = 1.0f / s;             // s uniform across the 8-lane group
    *reinterpret_cast<float4*>(out + (size_t)row * DDIM + (size_t)l * 4) =
        make_float4(ux * is, uy * is, uz * is, uw * is);
}

extern "C" void kernel_launch(void* const* d_in, const int* in_sizes, int n_in,
                              void* d_out, int out_size, void* d_ws, size_t ws_size,
                              hipStream_t stream) {
    const float* features = (const float*)d_in[0];
    const float* neigh    = (const float*)d_in[1];
    float* out            = (float*)d_out;
    const int B = in_sizes[0] / DDIM;
    homo_attn_kernel<<<(B + 3) / 4, 256, 0, stream>>>(features, neigh, out, B);
}

// Round 3
// 97.446 us; speedup vs baseline: 1.2502x; 1.1399x over previous
//
#include <hip/hip_runtime.h>
#include <math.h>

#define NBR   64
#define DDIM  256

typedef float f32x4 __attribute__((ext_vector_type(4)));

// Sum over each aligned 8-lane group (lanes sharing l>>3), broadcast to all
// 8 lanes. Pure VALU: quad_perm xor1, quad_perm xor2, then ROW_HALF_MIRROR
// (lane i <- i^7; after the quad reduce the value is quad-uniform, and i^7
// is in the other quad of the same 8-group). No DS ops, no lgkmcnt waits.
__device__ __forceinline__ float grp8_sum(float v) {
    v += __int_as_float(__builtin_amdgcn_update_dpp(
            0, __float_as_int(v), 0xB1, 0xF, 0xF, true));   // quad_perm xor 1
    v += __int_as_float(__builtin_amdgcn_update_dpp(
            0, __float_as_int(v), 0x4E, 0xF, 0xF, true));   // quad_perm xor 2
    v += __int_as_float(__builtin_amdgcn_update_dpp(
            0, __float_as_int(v), 0x141, 0xF, 0xF, true));  // row_half_mirror
    return v;
}

// One WAVE per batch row. Lane l owns facet f = l>>3, elems (l&7)*4 .. +3.
// Single streaming pass; unshifted softmax (cosine logits in [-1,1]).
// Neighbor stream loaded non-temporally (zero reuse -> don't pollute L2/LLC).
__global__ __launch_bounds__(256, 8) void homo_attn_kernel(
    const float* __restrict__ features,      // [B, 256]
    const float* __restrict__ neigh,         // [B, 64, 256]
    float* __restrict__ out,                 // [B, 256]
    int B)
{
    const int row = (blockIdx.x << 2) + (threadIdx.x >> 6);  // one wave = one b
    if (row >= B) return;
    const int l = threadIdx.x & 63;

    // ---- x fragment: load + l2-normalize ----
    const f32x4 x4 = *reinterpret_cast<const f32x4*>(
        features + (size_t)row * DDIM + (size_t)l * 4);
    const float xs = grp8_sum(x4.x * x4.x + x4.y * x4.y + x4.z * x4.z + x4.w * x4.w);
    const float xinv = __frsqrt_rn(fmaxf(xs, 1e-24f));
    const float xnx = x4.x * xinv, xny = x4.y * xinv;
    const float xnz = x4.z * xinv, xnw = x4.w * xinv;

    const float* zp = neigh + (size_t)row * (NBR * DDIM) + (size_t)l * 4;

    // ---- single pass over neighbors: logits + online weighted sum ----
    float ux = 0.0f, uy = 0.0f, uz = 0.0f, uw = 0.0f, s = 0.0f;
    #pragma unroll 4
    for (int n = 0; n < NBR; ++n) {
        const f32x4 z4 = __builtin_nontemporal_load(
            reinterpret_cast<const f32x4*>(zp + (size_t)n * DDIM));
        const float zs = grp8_sum(z4.x * z4.x + z4.y * z4.y + z4.z * z4.z + z4.w * z4.w);
        const float zinv = __frsqrt_rn(fmaxf(zs, 1e-24f));   // uniform in group
        const float dt = grp8_sum(z4.x * xnx + z4.y * xny +
                                  z4.z * xnz + z4.w * xnw) * zinv;  // cosine
        const float p = __expf(dt);        // |dt| <= 1: no max shift needed
        const float w = p * zinv;          // fold z-normalization into weight
        s  += p;
        ux += w * z4.x; uy += w * z4.y; uz += w * z4.z; uw += w * z4.w;
    }

    const float is = 1.0f / s;             // s uniform across the 8-lane group
    f32x4 o; o.x = ux * is; o.y = uy * is; o.z = uz * is; o.w = uw * is;
    *reinterpret_cast<f32x4*>(out + (size_t)row * DDIM + (size_t)l * 4) = o;
}

extern "C" void kernel_launch(void* const* d_in, const int* in_sizes, int n_in,
                              void* d_out, int out_size, void* d_ws, size_t ws_size,
                              hipStream_t stream) {
    const float* features = (const float*)d_in[0];
    const float* neigh    = (const float*)d_in[1];
    float* out            = (float*)d_out;
    const int B = in_sizes[0] / DDIM;
    homo_attn_kernel<<<(B + 3) / 4, 256, 0, stream>>>(features, neigh, out, B);
}

// Round 4
// 91.219 us; speedup vs baseline: 1.3355x; 1.0683x over previous
//
#include <hip/hip_runtime.h>
#include <math.h>

#define NBR   64
#define DDIM  256

typedef float f32x4 __attribute__((ext_vector_type(4)));

// Sum over each aligned 8-lane group (lanes sharing l>>3), broadcast to all
// 8 lanes. Pure VALU: quad_perm xor1, quad_perm xor2, then ROW_HALF_MIRROR
// (lane i <- i^7). No DS ops, no lgkmcnt waits. (Verified R3, absmax 2.4e-4.)
__device__ __forceinline__ float grp8_sum(float v) {
    v += __int_as_float(__builtin_amdgcn_update_dpp(
            0, __float_as_int(v), 0xB1, 0xF, 0xF, true));   // quad_perm xor 1
    v += __int_as_float(__builtin_amdgcn_update_dpp(
            0, __float_as_int(v), 0x4E, 0xF, 0xF, true));   // quad_perm xor 2
    v += __int_as_float(__builtin_amdgcn_update_dpp(
            0, __float_as_int(v), 0x141, 0xF, 0xF, true));  // row_half_mirror
    return v;
}

// One BLOCK (4 waves) per batch row. Wave g handles neighbors n = 4t + g,
// t = 0..15, so the block's instantaneous HBM footprint is a CONTIGUOUS 4 KB
// window sweeping the row's 64 KB (DRAM row-buffer friendly), instead of one
// wave crawling a private 1 KB-granular stream.
// Unshifted softmax (cosine logits in [-1,1]) -> per-wave partial (s, u)
// combine exactly: one final barrier + 4-way LDS reduce, no mid-loop sync.
__global__ __launch_bounds__(256, 8) void homo_attn_kernel(
    const float* __restrict__ features,      // [B, 256]
    const float* __restrict__ neigh,         // [B, 64, 256]
    float* __restrict__ out,                 // [B, 256]
    int B)
{
    const int b   = blockIdx.x;
    const int tid = threadIdx.x;
    const int g   = tid >> 6;   // wave 0..3
    const int l   = tid & 63;   // lane
    const int f   = l >> 3;     // facet 0..7

    __shared__ f32x4 sU[4][64];   // per-wave partial u rows, 4 KB
    __shared__ float sS[4][8];    // per-wave partial softmax sums per facet

    // ---- x fragment: load + l2-normalize (same row for all 4 waves; the
    // 3 redundant reads hit L1/L2, not HBM) ----
    const f32x4 x4 = *reinterpret_cast<const f32x4*>(
        features + (size_t)b * DDIM + (size_t)l * 4);
    const float xs = grp8_sum(x4.x * x4.x + x4.y * x4.y + x4.z * x4.z + x4.w * x4.w);
    const float xinv = __frsqrt_rn(fmaxf(xs, 1e-24f));
    const float xnx = x4.x * xinv, xny = x4.y * xinv;
    const float xnz = x4.z * xinv, xnw = x4.w * xinv;

    // wave g, iter t reads neighbor n = 4t + g
    const float* zp = neigh + (size_t)b * (NBR * DDIM)
                            + (size_t)g * DDIM + (size_t)l * 4;

    float ux = 0.0f, uy = 0.0f, uz = 0.0f, uw = 0.0f, s = 0.0f;
    #pragma unroll 4
    for (int t = 0; t < 16; ++t) {
        const f32x4 z4 = __builtin_nontemporal_load(
            reinterpret_cast<const f32x4*>(zp + (size_t)t * (4 * DDIM)));
        const float zs = grp8_sum(z4.x * z4.x + z4.y * z4.y + z4.z * z4.z + z4.w * z4.w);
        const float zinv = __frsqrt_rn(fmaxf(zs, 1e-24f));   // uniform in group
        const float dt = grp8_sum(z4.x * xnx + z4.y * xny +
                                  z4.z * xnz + z4.w * xnw) * zinv;  // cosine
        const float p = __expf(dt);        // |dt| <= 1: no max shift needed
        const float w = p * zinv;          // fold z-normalization into weight
        s  += p;
        ux += w * z4.x; uy += w * z4.y; uz += w * z4.z; uw += w * z4.w;
    }

    f32x4 up; up.x = ux; up.y = uy; up.z = uz; up.w = uw;
    sU[g][l] = up;
    if ((l & 7) == 0) sS[g][f] = s;
    __syncthreads();

    // ---- combine 4 wave-partials; thread tid owns output element tid ----
    const float* su = reinterpret_cast<const float*>(sU);
    const float v = su[tid] + su[256 + tid] + su[512 + tid] + su[768 + tid];
    const int ff = tid >> 5;   // facet of output element tid
    const float st = sS[0][ff] + sS[1][ff] + sS[2][ff] + sS[3][ff];
    out[(size_t)b * DDIM + tid] = v / st;
}

extern "C" void kernel_launch(void* const* d_in, const int* in_sizes, int n_in,
                              void* d_out, int out_size, void* d_ws, size_t ws_size,
                              hipStream_t stream) {
    const float* features = (const float*)d_in[0];
    const float* neigh    = (const float*)d_in[1];
    float* out            = (float*)d_out;
    const int B = in_sizes[0] / DDIM;
    homo_attn_kernel<<<B, 256, 0, stream>>>(features, neigh, out, B);
}

// Round 5
// 90.936 us; speedup vs baseline: 1.3397x; 1.0031x over previous
//
#include <hip/hip_runtime.h>
#include <math.h>

#define NBR   64
#define DDIM  256

typedef float f32x4 __attribute__((ext_vector_type(4)));

// Sum over each aligned 8-lane group (lanes sharing l>>3), broadcast to all
// 8 lanes. Pure VALU: quad_perm xor1, quad_perm xor2, then ROW_HALF_MIRROR
// (lane i <- i^7). No DS ops, no lgkmcnt waits. (Verified R2-R4.)
__device__ __forceinline__ float grp8_sum(float v) {
    v += __int_as_float(__builtin_amdgcn_update_dpp(
            0, __float_as_int(v), 0xB1, 0xF, 0xF, true));   // quad_perm xor 1
    v += __int_as_float(__builtin_amdgcn_update_dpp(
            0, __float_as_int(v), 0x4E, 0xF, 0xF, true));   // quad_perm xor 2
    v += __int_as_float(__builtin_amdgcn_update_dpp(
            0, __float_as_int(v), 0x141, 0xF, 0xF, true));  // row_half_mirror
    return v;
}

// One BLOCK (4 waves) per batch row. Wave g owns neighbor PAIRS
// n = 8t + 2g, 8t + 2g + 1 (t = 0..7): each wave issues 2 KB contiguous per
// iteration and the block's instantaneous HBM window is 8 KB contiguous
// sweeping the row's 64 KB — maximizes DRAM burst locality.
// Unshifted softmax (cosine logits in [-1,1]) -> per-wave partials (s, u)
// combine exactly: one final barrier + 4-way LDS reduce.
__global__ __launch_bounds__(256, 8) void homo_attn_kernel(
    const float* __restrict__ features,      // [B, 256]
    const float* __restrict__ neigh,         // [B, 64, 256]
    float* __restrict__ out,                 // [B, 256]
    int B)
{
    const int b   = blockIdx.x;
    const int tid = threadIdx.x;
    const int g   = tid >> 6;   // wave 0..3
    const int l   = tid & 63;   // lane
    const int f   = l >> 3;     // facet 0..7

    __shared__ f32x4 sU[4][64];   // per-wave partial u rows, 4 KB
    __shared__ float sS[4][8];    // per-wave partial softmax sums per facet

    // ---- x fragment: load + l2-normalize (same row for all 4 waves; the
    // 3 redundant reads hit L1/L2, not HBM) ----
    const f32x4 x4 = *reinterpret_cast<const f32x4*>(
        features + (size_t)b * DDIM + (size_t)l * 4);
    const float xs = grp8_sum(x4.x * x4.x + x4.y * x4.y + x4.z * x4.z + x4.w * x4.w);
    const float xinv = __frsqrt_rn(fmaxf(xs, 1e-24f));
    const float xnx = x4.x * xinv, xny = x4.y * xinv;
    const float xnz = x4.z * xinv, xnw = x4.w * xinv;

    // wave g, iter t reads neighbors n0 = 8t + 2g and n0 + 1
    const float* zp = neigh + (size_t)b * (NBR * DDIM)
                            + (size_t)(2 * g) * DDIM + (size_t)l * 4;

    float ux = 0.0f, uy = 0.0f, uz = 0.0f, uw = 0.0f, s = 0.0f;
    #pragma unroll 2
    for (int t = 0; t < 8; ++t) {
        const float* p0 = zp + (size_t)t * (8 * DDIM);
        const f32x4 a4 = __builtin_nontemporal_load(
            reinterpret_cast<const f32x4*>(p0));
        const f32x4 b4 = __builtin_nontemporal_load(
            reinterpret_cast<const f32x4*>(p0 + DDIM));

        const float as = grp8_sum(a4.x * a4.x + a4.y * a4.y + a4.z * a4.z + a4.w * a4.w);
        const float bs = grp8_sum(b4.x * b4.x + b4.y * b4.y + b4.z * b4.z + b4.w * b4.w);
        const float ainv = __frsqrt_rn(fmaxf(as, 1e-24f));
        const float binv = __frsqrt_rn(fmaxf(bs, 1e-24f));
        const float da = grp8_sum(a4.x * xnx + a4.y * xny +
                                  a4.z * xnz + a4.w * xnw) * ainv;
        const float db = grp8_sum(b4.x * xnx + b4.y * xny +
                                  b4.z * xnz + b4.w * xnw) * binv;
        const float pa = __expf(da);       // |d| <= 1: no max shift needed
        const float pb = __expf(db);
        const float wa = pa * ainv;        // fold z-normalization into weight
        const float wb = pb * binv;
        s  += pa + pb;
        ux += wa * a4.x + wb * b4.x;
        uy += wa * a4.y + wb * b4.y;
        uz += wa * a4.z + wb * b4.z;
        uw += wa * a4.w + wb * b4.w;
    }

    f32x4 up; up.x = ux; up.y = uy; up.z = uz; up.w = uw;
    sU[g][l] = up;
    if ((l & 7) == 0) sS[g][f] = s;
    __syncthreads();

    // ---- combine 4 wave-partials; thread tid owns output element tid ----
    const float* su = reinterpret_cast<const float*>(sU);
    const float v = su[tid] + su[256 + tid] + su[512 + tid] + su[768 + tid];
    const int ff = tid >> 5;   // facet of output element tid
    const float st = sS[0][ff] + sS[1][ff] + sS[2][ff] + sS[3][ff];
    out[(size_t)b * DDIM + tid] = v / st;
}

extern "C" void kernel_launch(void* const* d_in, const int* in_sizes, int n_in,
                              void* d_out, int out_size, void* d_ws, size_t ws_size,
                              hipStream_t stream) {
    const float* features = (const float*)d_in[0];
    const float* neigh    = (const float*)d_in[1];
    float* out            = (float*)d_out;
    const int B = in_sizes[0] / DDIM;
    homo_attn_kernel<<<B, 256, 0, stream>>>(features, neigh, out, B);
}